// Round 10
// baseline (302.882 us; speedup 1.0000x reference)
//
#include <hip/hip_runtime.h>

#define N_NODES 50000
#define N_EDGES 800000
#define DIM 128
#define MAXDEG 64                  // Poisson(16) tail: P(deg>=64) ~ 1e-19
#define EDGE_BLOCKS ((N_EDGES + 255) / 256)
#define WT_BLOCKS 192              // 3 * 128*128 / 256
#define GEMM_BLOCKS ((N_NODES + 127) / 128)
#define ZERO_ROW N_NODES           // h row used by padding slots (kept all-zero)

typedef unsigned int u32;
typedef short bf16x8 __attribute__((ext_vector_type(8)));
typedef float f32x4 __attribute__((ext_vector_type(4)));

static inline size_t alignUp(size_t x) { return (x + 255) & ~size_t(255); }

// fp32 -> bf16 round-to-nearest-even (finite values)
__device__ inline unsigned short f2bf(float f) {
    union { float f; u32 u; } v; v.f = f;
    u32 r = v.u + 0x7fffu + ((v.u >> 16) & 1u);
    return (unsigned short)(r >> 16);
}
__device__ inline float bf_lo(u32 u) { return __uint_as_float(u << 16); }
__device__ inline float bf_hi(u32 u) { return __uint_as_float(u & 0xffff0000u); }

// ---------------- fused: W->bf16 transpose + edge scatter (direct-mapped) ----------------
__global__ __launch_bounds__(256) void prep_kernel(const float* __restrict__ W1,
                                                   const float* __restrict__ W2,
                                                   const float* __restrict__ W3,
                                                   unsigned short* __restrict__ Wt,
                                                   const int* __restrict__ src,
                                                   const int* __restrict__ dst,
                                                   int* __restrict__ cursor,
                                                   int* __restrict__ csr_dm) {
    int bid = blockIdx.x;
    if (bid < WT_BLOCKS) {
        int m = bid >> 6;
        int e = (bid & 63) * 256 + threadIdx.x;
        int n = e >> 7, k = e & 127;
        const float* W = (m == 0) ? W1 : (m == 1) ? W2 : W3;
        Wt[m * DIM * DIM + n * DIM + k] = f2bf(W[(size_t)k * DIM + n]);
        return;
    }
    int i = (bid - WT_BLOCKS) * 256 + threadIdx.x;
    if (i < N_EDGES) {
        int d = dst[i];
        int pos = atomicAdd(&cursor[d], 1);
        if (pos < MAXDEG) csr_dm[d * MAXDEG + pos] = src[i];
    }
}

// ---------------- finalize: dinv + pad csr rows to multiple of 16 with ZERO_ROW ----------------
__global__ __launch_bounds__(256) void finalize_kernel(const int* __restrict__ cnt,
                                                       int* __restrict__ csr_dm,
                                                       float* __restrict__ dinv) {
    int wave = threadIdx.x >> 6;
    int lane = threadIdx.x & 63;
    int node = blockIdx.x * 4 + wave;
    if (node >= N_NODES) return;
    int c = cnt[node];
    int m = min(c, MAXDEG);
    int m_pad = (m + 15) & ~15;
    if (lane == 0) dinv[node] = rsqrtf((float)(c + 1));   // +1 self-loop
    int j = m + lane;                                      // pad span <= 15 slots
    if (j < m_pad) csr_dm[node * MAXDEG + j] = ZERO_ROW;
}

// ---------------- MFMA GEMM: h'(bf16) = dinv .* (x @ Wt^T) ----------------
#define LDSTRIDE 40
__device__ void gemm_core(unsigned short* As, unsigned short* Bs,
                          const unsigned short* __restrict__ Wt,
                          const float* __restrict__ dinv,
                          unsigned short* __restrict__ hb, int n_rows, int row0,
                          bool stage_f32, const float* xf, const unsigned short* xb) {
    const int tid = threadIdx.x;
    const int wave = tid >> 6;
    const int lane = tid & 63;
    const int quad = lane >> 4;
    const int l16 = lane & 15;

    f32x4 acc[2][8];
#pragma unroll
    for (int mt = 0; mt < 2; mt++)
#pragma unroll
        for (int nt = 0; nt < 8; nt++) acc[mt][nt] = (f32x4){0.f, 0.f, 0.f, 0.f};

    for (int k0 = 0; k0 < DIM; k0 += 32) {
        if (stage_f32) {
#pragma unroll
            for (int p = 0; p < 4; p++) {
                int r = p * 32 + (tid >> 3);
                int kq = (tid & 7) * 4;
                int gr = row0 + r;
                float4 v = make_float4(0.f, 0.f, 0.f, 0.f);
                if (gr < n_rows) v = *(const float4*)&xf[(size_t)gr * DIM + k0 + kq];
                u32 lo = (u32)f2bf(v.x) | ((u32)f2bf(v.y) << 16);
                u32 hi = (u32)f2bf(v.z) | ((u32)f2bf(v.w) << 16);
                *(uint2*)&As[r * LDSTRIDE + kq] = make_uint2(lo, hi);
            }
        } else {
#pragma unroll
            for (int p = 0; p < 2; p++) {
                int idx = p * 256 + tid;
                int r = idx >> 2;
                int c = idx & 3;
                int gr = row0 + r;
                uint4 v = make_uint4(0, 0, 0, 0);
                if (gr < n_rows) v = *(const uint4*)&xb[(size_t)gr * DIM + k0 + c * 8];
                *(uint4*)&As[r * LDSTRIDE + c * 8] = v;
            }
        }
#pragma unroll
        for (int p = 0; p < 2; p++) {
            int nn = p * 64 + (tid >> 2);
            int kk = (tid & 3) * 8;
            *(uint4*)&Bs[nn * LDSTRIDE + kk] = *(const uint4*)&Wt[nn * DIM + k0 + kk];
        }
        __syncthreads();
        const int m0 = wave * 32;
        bf16x8 a0 = *(const bf16x8*)&As[(m0 + l16) * LDSTRIDE + quad * 8];
        bf16x8 a1 = *(const bf16x8*)&As[(m0 + 16 + l16) * LDSTRIDE + quad * 8];
#pragma unroll
        for (int nt = 0; nt < 8; nt++) {
            bf16x8 b = *(const bf16x8*)&Bs[(nt * 16 + l16) * LDSTRIDE + quad * 8];
            acc[0][nt] = __builtin_amdgcn_mfma_f32_16x16x32_bf16(a0, b, acc[0][nt], 0, 0, 0);
            acc[1][nt] = __builtin_amdgcn_mfma_f32_16x16x32_bf16(a1, b, acc[1][nt], 0, 0, 0);
        }
        __syncthreads();
    }
    const int m0 = wave * 32;
#pragma unroll
    for (int mt = 0; mt < 2; mt++) {
#pragma unroll
        for (int reg = 0; reg < 4; reg++) {
            int gr = row0 + m0 + mt * 16 + quad * 4 + reg;
            if (gr < n_rows) {
                float dv = dinv[gr];
#pragma unroll
                for (int nt = 0; nt < 8; nt++)
                    hb[(size_t)gr * DIM + nt * 16 + l16] = f2bf(dv * acc[mt][nt][reg]);
            }
        }
    }
}

__global__ __launch_bounds__(256) void gemm_f32_kernel(const float* __restrict__ x,
                                                       const unsigned short* __restrict__ Wt,
                                                       const float* __restrict__ dinv,
                                                       unsigned short* __restrict__ hb, int n) {
    __shared__ unsigned short As[128 * LDSTRIDE];
    __shared__ unsigned short Bs[128 * LDSTRIDE];
    gemm_core(As, Bs, Wt, dinv, hb, n, blockIdx.x * 128, true, x, nullptr);
}

__global__ __launch_bounds__(256) void gemm_bf16_kernel(const unsigned short* __restrict__ x,
                                                        const unsigned short* __restrict__ Wt,
                                                        const float* __restrict__ dinv,
                                                        unsigned short* __restrict__ hb, int n) {
    __shared__ unsigned short As[128 * LDSTRIDE];
    __shared__ unsigned short Bs[128 * LDSTRIDE];
    gemm_core(As, Bs, Wt, dinv, hb, n, blockIdx.x * 128, false, nullptr, x);
}

// ---------------- aggregation: pure unweighted row-sum over h' ----------------
// out[i] = dinv[i]*(sum_{s in nbr} h'[s] + h'[i]) + b,   h' = dinv .* h
// Wave per node = 4 groups x 16 lanes; group g takes neighbors j0+g,+4+g,+8+g,+12+g.
// csr rows padded to multiple of 16 with ZERO_ROW (one always-hot zero line).
__device__ inline void add8(float acc[8], uint4 r) {
    acc[0] += bf_lo(r.x); acc[1] += bf_hi(r.x);
    acc[2] += bf_lo(r.y); acc[3] += bf_hi(r.y);
    acc[4] += bf_lo(r.z); acc[5] += bf_hi(r.z);
    acc[6] += bf_lo(r.w); acc[7] += bf_hi(r.w);
}

__global__ __launch_bounds__(256) void agg_kernel(const uint4* __restrict__ hb,
                                                  const int* __restrict__ cnt,
                                                  const int* __restrict__ csr,
                                                  const float4* __restrict__ bias4,
                                                  unsigned short* __restrict__ out_bf,
                                                  float* __restrict__ out_f32,
                                                  int relu_bf16) {
    const int wave = threadIdx.x >> 6;
    const int lane = threadIdx.x & 63;
    const int node = blockIdx.x * 4 + wave;
    const int g = lane >> 4;
    const int l16 = lane & 15;

    const int c = cnt[node];
    const float di = rsqrtf((float)(c + 1));
    const int m = min(c, MAXDEG);
    const int m_pad = (m + 15) & ~15;
    const int* cp = csr + node * MAXDEG;

    float acc[8];
#pragma unroll
    for (int i = 0; i < 8; i++) acc[i] = 0.f;

    for (int j0 = 0; j0 < m_pad; j0 += 16) {
        int sA = cp[j0 + g];
        int sB = cp[j0 + 4 + g];
        int sC = cp[j0 + 8 + g];
        int sD = cp[j0 + 12 + g];
        uint4 rA = hb[(size_t)sA * 16 + l16];
        uint4 rB = hb[(size_t)sB * 16 + l16];
        uint4 rC = hb[(size_t)sC * 16 + l16];
        uint4 rD = hb[(size_t)sD * 16 + l16];
        add8(acc, rA);
        add8(acc, rB);
        add8(acc, rC);
        add8(acc, rD);
    }
    if (g == 0) {   // self term: + h'[node]
        uint4 r = hb[(size_t)node * 16 + l16];
        add8(acc, r);
    }
#pragma unroll
    for (int i = 0; i < 8; i++) {
        acc[i] += __shfl_xor(acc[i], 16, 64);
        acc[i] += __shfl_xor(acc[i], 32, 64);
    }
    if (g == 0) {   // lanes 0..15: features l16*8 .. +7
        float4 b0 = bias4[l16 * 2], b1 = bias4[l16 * 2 + 1];
        float v[8];
        v[0] = di * acc[0] + b0.x; v[1] = di * acc[1] + b0.y;
        v[2] = di * acc[2] + b0.z; v[3] = di * acc[3] + b0.w;
        v[4] = di * acc[4] + b1.x; v[5] = di * acc[5] + b1.y;
        v[6] = di * acc[6] + b1.z; v[7] = di * acc[7] + b1.w;
        if (relu_bf16) {
            uint4 pk;
            u32* p = (u32*)&pk;
#pragma unroll
            for (int i = 0; i < 4; i++) {
                float a = fmaxf(v[2 * i], 0.f), b = fmaxf(v[2 * i + 1], 0.f);
                p[i] = (u32)f2bf(a) | ((u32)f2bf(b) << 16);
            }
            ((uint4*)(out_bf + (size_t)node * DIM))[l16] = pk;
        } else {
            float4* o = (float4*)(out_f32 + (size_t)node * DIM);
            o[l16 * 2] = make_float4(v[0], v[1], v[2], v[3]);
            o[l16 * 2 + 1] = make_float4(v[4], v[5], v[6], v[7]);
        }
    }
}

// ---------------- launch ----------------

extern "C" void kernel_launch(void* const* d_in, const int* in_sizes, int n_in,
                              void* d_out, int out_size, void* d_ws, size_t ws_size,
                              hipStream_t stream) {
    const float* x  = (const float*)d_in[0];
    const int* ei   = (const int*)d_in[1];
    const float* W1 = (const float*)d_in[2];
    const float* b1 = (const float*)d_in[3];
    const float* W2 = (const float*)d_in[4];
    const float* b2 = (const float*)d_in[5];
    const float* W3 = (const float*)d_in[6];
    const float* b3 = (const float*)d_in[7];
    const int* src = ei;
    const int* dst = ei + N_EDGES;
    float* out = (float*)d_out;

    char* w = (char*)d_ws;
    int* cursor = (int*)w; w += alignUp((size_t)N_NODES * 4);                 // degree counts
    int* csr_dm = (int*)w; w += alignUp((size_t)N_NODES * MAXDEG * 4);        // 12.8 MB
    float* dinv = (float*)w; w += alignUp((size_t)N_NODES * 4);
    unsigned short* wt = (unsigned short*)w; w += alignUp((size_t)3 * DIM * DIM * 2);
    unsigned short* hbuf = (unsigned short*)w; w += alignUp((size_t)(N_NODES + 1) * DIM * 2);
    unsigned short* gbuf = (unsigned short*)w; w += alignUp((size_t)N_NODES * DIM * 2);

    hipMemsetAsync(cursor, 0, (size_t)N_NODES * 4, stream);
    hipMemsetAsync(hbuf + (size_t)ZERO_ROW * DIM, 0, DIM * 2, stream);  // the pad row

    prep_kernel<<<WT_BLOCKS + EDGE_BLOCKS, 256, 0, stream>>>(W1, W2, W3, wt, src, dst,
                                                             cursor, csr_dm);
    finalize_kernel<<<(N_NODES + 3) / 4, 256, 0, stream>>>(cursor, csr_dm, dinv);

    int ablocks = (N_NODES + 3) / 4;   // wave per node

    gemm_f32_kernel<<<GEMM_BLOCKS, 256, 0, stream>>>(x, wt, dinv, hbuf, N_NODES);
    agg_kernel<<<ablocks, 256, 0, stream>>>((const uint4*)hbuf, cursor, csr_dm,
                                            (const float4*)b1, gbuf, nullptr, 1);

    gemm_bf16_kernel<<<GEMM_BLOCKS, 256, 0, stream>>>(gbuf, wt + DIM * DIM, dinv, hbuf, N_NODES);
    agg_kernel<<<ablocks, 256, 0, stream>>>((const uint4*)hbuf, cursor, csr_dm,
                                            (const float4*)b2, gbuf, nullptr, 1);

    gemm_bf16_kernel<<<GEMM_BLOCKS, 256, 0, stream>>>(gbuf, wt + 2 * DIM * DIM, dinv, hbuf, N_NODES);
    agg_kernel<<<ablocks, 256, 0, stream>>>((const uint4*)hbuf, cursor, csr_dm,
                                            (const float4*)b3, nullptr, out, 0);
}

// Round 11
// 290.720 us; speedup vs baseline: 1.0418x; 1.0418x over previous
//
#include <hip/hip_runtime.h>

#define N_NODES 50000
#define N_EDGES 800000
#define DIM 128
#define MAXDEG 64                  // Poisson(16) tail: P(deg>=64) ~ 1e-19
#define ZERO_ROW N_NODES           // all-zero h row used by padding slots
#define GEMM_BLOCKS 391            // ceil(50000/128)
#define SCAT_BLOCKS 3125           // 800000/256
#define WT_BLOCKS 128              // W2,W3 -> bf16 transpose (W1 handled in-gemm)
#define FUSED_BLOCKS (GEMM_BLOCKS + SCAT_BLOCKS + WT_BLOCKS)   // 3644

typedef unsigned int u32;
typedef short bf16x8 __attribute__((ext_vector_type(8)));
typedef float f32x4 __attribute__((ext_vector_type(4)));

static inline size_t alignUp(size_t x) { return (x + 255) & ~size_t(255); }

__device__ inline unsigned short f2bf(float f) {
    union { float f; u32 u; } v; v.f = f;
    u32 r = v.u + 0x7fffu + ((v.u >> 16) & 1u);
    return (unsigned short)(r >> 16);
}
__device__ inline float bf_lo(u32 u) { return __uint_as_float(u << 16); }
__device__ inline float bf_hi(u32 u) { return __uint_as_float(u & 0xffff0000u); }

#define LDSTRIDE 40   // shorts; 80B row stride -> 2-way bank alias (free)

__device__ inline void mfma_tile(const unsigned short* As, const unsigned short* Bs,
                                 f32x4 acc[2][8], int wave, int quad, int l16) {
    const int m0 = wave * 32;
    bf16x8 a0 = *(const bf16x8*)&As[(m0 + l16) * LDSTRIDE + quad * 8];
    bf16x8 a1 = *(const bf16x8*)&As[(m0 + 16 + l16) * LDSTRIDE + quad * 8];
#pragma unroll
    for (int nt = 0; nt < 8; nt++) {
        bf16x8 b = *(const bf16x8*)&Bs[(nt * 16 + l16) * LDSTRIDE + quad * 8];
        acc[0][nt] = __builtin_amdgcn_mfma_f32_16x16x32_bf16(a0, b, acc[0][nt], 0, 0, 0);
        acc[1][nt] = __builtin_amdgcn_mfma_f32_16x16x32_bf16(a1, b, acc[1][nt], 0, 0, 0);
    }
}

// ---------------- fused: gemm1 (1-in-9 interleave) + edge scatter + W2/W3 transpose --------
__global__ __launch_bounds__(256) void prep_kernel(const float* __restrict__ x,
                                                   const float* __restrict__ W1,
                                                   const float* __restrict__ W2,
                                                   const float* __restrict__ W3,
                                                   unsigned short* __restrict__ Wt,
                                                   const int* __restrict__ src,
                                                   const int* __restrict__ dst,
                                                   int* __restrict__ cursor,
                                                   int* __restrict__ csr_dm,
                                                   unsigned short* __restrict__ h1) {
    __shared__ unsigned short As[128 * LDSTRIDE];
    __shared__ unsigned short Bs[128 * LDSTRIDE];
    const int bid = blockIdx.x;
    const int tid = threadIdx.x;
    const int q = bid / 9, r9 = bid % 9;

    if (r9 == 8 && q < GEMM_BLOCKS) {
        // ---- gemm1: h1(bf16, unscaled) = bf16(x) @ bf16(W1)  (B transposed on the fly)
        const int wave = tid >> 6, lane = tid & 63;
        const int quad = lane >> 4, l16 = lane & 15;
        const int row0 = q * 128;
        f32x4 acc[2][8];
#pragma unroll
        for (int mt = 0; mt < 2; mt++)
#pragma unroll
            for (int nt = 0; nt < 8; nt++) acc[mt][nt] = (f32x4){0.f, 0.f, 0.f, 0.f};

        for (int k0 = 0; k0 < DIM; k0 += 32) {
#pragma unroll
            for (int p = 0; p < 4; p++) {   // A: 128r x 32k fp32->bf16
                int r = p * 32 + (tid >> 3);
                int kq = (tid & 7) * 4;
                int gr = row0 + r;
                float4 v = make_float4(0.f, 0.f, 0.f, 0.f);
                if (gr < N_NODES) v = *(const float4*)&x[(size_t)gr * DIM + k0 + kq];
                u32 lo = (u32)f2bf(v.x) | ((u32)f2bf(v.y) << 16);
                u32 hi = (u32)f2bf(v.z) | ((u32)f2bf(v.w) << 16);
                *(uint2*)&As[r * LDSTRIDE + kq] = make_uint2(lo, hi);
            }
#pragma unroll
            for (int p = 0; p < 2; p++) {   // B: Bs[n][k] = bf16(W1[k][n])
                int nn = p * 64 + (tid >> 2);
                int kb = (tid & 3) * 8;
                u32 pk[4];
#pragma unroll
                for (int i = 0; i < 4; i++) {
                    float a = W1[(size_t)(k0 + kb + 2 * i) * DIM + nn];
                    float b = W1[(size_t)(k0 + kb + 2 * i + 1) * DIM + nn];
                    pk[i] = (u32)f2bf(a) | ((u32)f2bf(b) << 16);
                }
                *(uint4*)&Bs[nn * LDSTRIDE + kb] = make_uint4(pk[0], pk[1], pk[2], pk[3]);
            }
            __syncthreads();
            mfma_tile(As, Bs, acc, wave, quad, l16);
            __syncthreads();
        }
        const int m0 = wave * 32;
#pragma unroll
        for (int mt = 0; mt < 2; mt++)
#pragma unroll
            for (int reg = 0; reg < 4; reg++) {
                int gr = row0 + m0 + mt * 16 + quad * 4 + reg;
                if (gr < N_NODES) {
#pragma unroll
                    for (int nt = 0; nt < 8; nt++)
                        h1[(size_t)gr * DIM + nt * 16 + l16] = f2bf(acc[mt][nt][reg]);
                }
            }
        return;
    }

    int other = (q < GEMM_BLOCKS) ? (bid - q) : (bid - GEMM_BLOCKS);
    if (other < SCAT_BLOCKS) {
        // ---- edge scatter into direct-mapped CSR; cursor doubles as degree
        int i = other * 256 + tid;
        if (i < N_EDGES) {
            int d = dst[i];
            int pos = atomicAdd(&cursor[d], 1);
            if (pos < MAXDEG) csr_dm[d * MAXDEG + pos] = src[i];
        }
        return;
    }
    // ---- W2/W3 -> bf16 transpose
    int wid = other - SCAT_BLOCKS;                // 0..127
    int m = wid >> 6;                             // 0 = W2, 1 = W3
    int e = (wid & 63) * 256 + tid;
    int n = e >> 7, k = e & 127;
    const float* W = m ? W3 : W2;
    Wt[m * DIM * DIM + n * DIM + k] = f2bf(W[(size_t)k * DIM + n]);
}

// ---------------- gemm layers 2,3: h'(bf16) = dinv .* (g(bf16) @ Wt^T) ----------------
__global__ __launch_bounds__(256) void gemm_bf16_kernel(const unsigned short* __restrict__ xb,
                                                        const unsigned short* __restrict__ Wt,
                                                        const float* __restrict__ dinv,
                                                        unsigned short* __restrict__ hb, int n) {
    __shared__ unsigned short As[128 * LDSTRIDE];
    __shared__ unsigned short Bs[128 * LDSTRIDE];
    const int tid = threadIdx.x;
    const int wave = tid >> 6, lane = tid & 63;
    const int quad = lane >> 4, l16 = lane & 15;
    const int row0 = blockIdx.x * 128;

    f32x4 acc[2][8];
#pragma unroll
    for (int mt = 0; mt < 2; mt++)
#pragma unroll
        for (int nt = 0; nt < 8; nt++) acc[mt][nt] = (f32x4){0.f, 0.f, 0.f, 0.f};

    for (int k0 = 0; k0 < DIM; k0 += 32) {
#pragma unroll
        for (int p = 0; p < 2; p++) {
            int idx = p * 256 + tid;
            int r = idx >> 2, c = idx & 3;
            int gr = row0 + r;
            uint4 v = make_uint4(0, 0, 0, 0);
            if (gr < n) v = *(const uint4*)&xb[(size_t)gr * DIM + k0 + c * 8];
            *(uint4*)&As[r * LDSTRIDE + c * 8] = v;
        }
#pragma unroll
        for (int p = 0; p < 2; p++) {
            int nn = p * 64 + (tid >> 2);
            int kk = (tid & 3) * 8;
            *(uint4*)&Bs[nn * LDSTRIDE + kk] = *(const uint4*)&Wt[nn * DIM + k0 + kk];
        }
        __syncthreads();
        mfma_tile(As, Bs, acc, wave, quad, l16);
        __syncthreads();
    }
    const int m0 = wave * 32;
#pragma unroll
    for (int mt = 0; mt < 2; mt++)
#pragma unroll
        for (int reg = 0; reg < 4; reg++) {
            int gr = row0 + m0 + mt * 16 + quad * 4 + reg;
            if (gr < n) {
                float dv = dinv[gr];
#pragma unroll
                for (int nt = 0; nt < 8; nt++)
                    hb[(size_t)gr * DIM + nt * 16 + l16] = f2bf(dv * acc[mt][nt][reg]);
            }
        }
}

// ---------------- aggregation: 16-lane GROUP per node, 8 rows in flight ----------------
// layer1: out = di*(sum dinv[s]*h1[s] + di*h1[i]) + b   (also emits dinv)
// else:   out = di*(sum h'[s] + h'[i]) + b              (h' pre-scaled by gemm)
__device__ inline void add8(float acc[8], uint4 r) {
    acc[0] += bf_lo(r.x); acc[1] += bf_hi(r.x);
    acc[2] += bf_lo(r.y); acc[3] += bf_hi(r.y);
    acc[4] += bf_lo(r.z); acc[5] += bf_hi(r.z);
    acc[6] += bf_lo(r.w); acc[7] += bf_hi(r.w);
}
__device__ inline void fma8(float acc[8], uint4 r, float w) {
    acc[0] += w * bf_lo(r.x); acc[1] += w * bf_hi(r.x);
    acc[2] += w * bf_lo(r.y); acc[3] += w * bf_hi(r.y);
    acc[4] += w * bf_lo(r.z); acc[5] += w * bf_hi(r.z);
    acc[6] += w * bf_lo(r.w); acc[7] += w * bf_hi(r.w);
}

__global__ __launch_bounds__(256) void agg_kernel(const uint4* __restrict__ hb,
                                                  const int* __restrict__ cnt,
                                                  const int* __restrict__ csr,
                                                  const float4* __restrict__ bias4,
                                                  unsigned short* __restrict__ out_bf,
                                                  float* __restrict__ out_f32,
                                                  float* __restrict__ dinv_out,
                                                  int layer1, int relu) {
    const int tid = threadIdx.x;
    const int grp = tid >> 4;              // 0..15, owns one node
    const int l16 = tid & 15;              // 16B chunk of the 256B row
    const int node = blockIdx.x * 16 + grp;   // grid = 3125 -> exact cover

    const int c = cnt[node];
    const float di = rsqrtf((float)(c + 1));
    const int m = min(c, MAXDEG);
    const int* cp = csr + node * MAXDEG;

    float acc[8];
#pragma unroll
    for (int i = 0; i < 8; i++) acc[i] = 0.f;

    if (layer1) {
        for (int j0 = 0; j0 < m; j0 += 8) {
            int s[8]; float w[8]; uint4 rr[8];
#pragma unroll
            for (int i = 0; i < 8; i++) {
                int j = j0 + i;
                s[i] = (j < m) ? cp[j] : ZERO_ROW;
            }
#pragma unroll
            for (int i = 0; i < 8; i++) rr[i] = hb[(size_t)s[i] * 16 + l16];
#pragma unroll
            for (int i = 0; i < 8; i++) {
                int j = j0 + i;
                w[i] = 0.f;
                if (j < m) w[i] = rsqrtf((float)(cnt[s[i]] + 1));
            }
#pragma unroll
            for (int i = 0; i < 8; i++) fma8(acc, rr[i], w[i]);
        }
        uint4 r = hb[(size_t)node * 16 + l16];
        fma8(acc, r, di);
        if (l16 == 0) dinv_out[node] = di;
    } else {
        for (int j0 = 0; j0 < m; j0 += 8) {
            int s[8]; uint4 rr[8];
#pragma unroll
            for (int i = 0; i < 8; i++) {
                int j = j0 + i;
                s[i] = (j < m) ? cp[j] : ZERO_ROW;
            }
#pragma unroll
            for (int i = 0; i < 8; i++) rr[i] = hb[(size_t)s[i] * 16 + l16];
#pragma unroll
            for (int i = 0; i < 8; i++) add8(acc, rr[i]);
        }
        uint4 r = hb[(size_t)node * 16 + l16];
        add8(acc, r);
    }

    float4 b0 = bias4[l16 * 2], b1 = bias4[l16 * 2 + 1];
    float v[8];
    v[0] = di * acc[0] + b0.x; v[1] = di * acc[1] + b0.y;
    v[2] = di * acc[2] + b0.z; v[3] = di * acc[3] + b0.w;
    v[4] = di * acc[4] + b1.x; v[5] = di * acc[5] + b1.y;
    v[6] = di * acc[6] + b1.z; v[7] = di * acc[7] + b1.w;
    if (relu) {
        uint4 pk;
        u32* p = (u32*)&pk;
#pragma unroll
        for (int i = 0; i < 4; i++) {
            float a = fmaxf(v[2 * i], 0.f), b = fmaxf(v[2 * i + 1], 0.f);
            p[i] = (u32)f2bf(a) | ((u32)f2bf(b) << 16);
        }
        ((uint4*)(out_bf + (size_t)node * DIM))[l16] = pk;
    } else {
        float4* o = (float4*)(out_f32 + (size_t)node * DIM);
        o[l16 * 2] = make_float4(v[0], v[1], v[2], v[3]);
        o[l16 * 2 + 1] = make_float4(v[4], v[5], v[6], v[7]);
    }
}

// ---------------- launch ----------------

extern "C" void kernel_launch(void* const* d_in, const int* in_sizes, int n_in,
                              void* d_out, int out_size, void* d_ws, size_t ws_size,
                              hipStream_t stream) {
    const float* x  = (const float*)d_in[0];
    const int* ei   = (const int*)d_in[1];
    const float* W1 = (const float*)d_in[2];
    const float* b1 = (const float*)d_in[3];
    const float* W2 = (const float*)d_in[4];
    const float* b2 = (const float*)d_in[5];
    const float* W3 = (const float*)d_in[6];
    const float* b3 = (const float*)d_in[7];
    const int* src = ei;
    const int* dst = ei + N_EDGES;
    float* out = (float*)d_out;

    char* w = (char*)d_ws;
    int* cursor = (int*)w; w += alignUp((size_t)N_NODES * 4);             // degree counts
    int* csr_dm = (int*)w; w += alignUp((size_t)N_NODES * MAXDEG * 4);    // 12.8 MB
    float* dinv = (float*)w; w += alignUp((size_t)N_NODES * 4);
    unsigned short* wt = (unsigned short*)w; w += alignUp((size_t)2 * DIM * DIM * 2);
    unsigned short* hbuf = (unsigned short*)w; w += alignUp((size_t)(N_NODES + 1) * DIM * 2);
    unsigned short* gbuf = (unsigned short*)w; w += alignUp((size_t)N_NODES * DIM * 2);

    hipMemsetAsync(cursor, 0, (size_t)N_NODES * 4, stream);
    hipMemsetAsync(hbuf + (size_t)ZERO_ROW * DIM, 0, DIM * 2, stream);   // pad row

    prep_kernel<<<FUSED_BLOCKS, 256, 0, stream>>>(x, W1, W2, W3, wt, src, dst,
                                                  cursor, csr_dm, hbuf);

    agg_kernel<<<N_NODES / 16, 256, 0, stream>>>((const uint4*)hbuf, cursor, csr_dm,
                                                 (const float4*)b1, gbuf, nullptr,
                                                 dinv, 1, 1);

    gemm_bf16_kernel<<<GEMM_BLOCKS, 256, 0, stream>>>(gbuf, wt, dinv, hbuf, N_NODES);
    agg_kernel<<<N_NODES / 16, 256, 0, stream>>>((const uint4*)hbuf, cursor, csr_dm,
                                                 (const float4*)b2, gbuf, nullptr,
                                                 nullptr, 0, 1);

    gemm_bf16_kernel<<<GEMM_BLOCKS, 256, 0, stream>>>(gbuf, wt + DIM * DIM, dinv, hbuf, N_NODES);
    agg_kernel<<<N_NODES / 16, 256, 0, stream>>>((const uint4*)hbuf, cursor, csr_dm,
                                                 (const float4*)b3, nullptr, out,
                                                 nullptr, 0, 0);
}